// Round 9
// baseline (124.080 us; speedup 1.0000x reference)
//
#include <hip/hip_runtime.h>
#include <stdint.h>

#define TOK 256
#define IN_F 4096
#define OUT_F 4096
#define N_OUT 32

typedef int v4i  __attribute__((ext_vector_type(4)));
typedef int v16i __attribute__((ext_vector_type(16)));

__device__ __forceinline__ void gll16(const void* g, void* l) {
    __builtin_amdgcn_global_load_lds((const __attribute__((address_space(1))) void*)g,
                                     (__attribute__((address_space(3))) void*)l, 16, 0, 0);
}

// ---------------- Kernel 1a: rowwise masked absmax + outlier gather ----------------
__global__ __launch_bounds__(256) void oal_absmax(
    const float* __restrict__ x, const int* __restrict__ oidx,
    float* __restrict__ xs, float* __restrict__ xo)
{
    const int row = blockIdx.x;
    const int tid = threadIdx.x;
    __shared__ unsigned char flags[IN_F];
    __shared__ float wmax[4];

    const float* xr = x + (size_t)row * IN_F;
    float4 v[4];
    const float4* xp = reinterpret_cast<const float4*>(xr + tid * 16);
    #pragma unroll
    for (int i = 0; i < 4; ++i) v[i] = xp[i];

    *reinterpret_cast<uint4*>(&flags[tid * 16]) = make_uint4(0u, 0u, 0u, 0u);
    __syncthreads();
    if (tid < N_OUT) flags[oidx[tid]] = 1;
    __syncthreads();

    uint4 f = *reinterpret_cast<const uint4*>(&flags[tid * 16]);
    unsigned int fw[4] = { f.x, f.y, f.z, f.w };
    float m = 0.0f;
    #pragma unroll
    for (int i = 0; i < 4; ++i) {
        float a0 = ((fw[i]      ) & 255u) ? 0.0f : v[i].x;
        float a1 = ((fw[i] >>  8) & 255u) ? 0.0f : v[i].y;
        float a2 = ((fw[i] >> 16) & 255u) ? 0.0f : v[i].z;
        float a3 = ((fw[i] >> 24) & 255u) ? 0.0f : v[i].w;
        m = fmaxf(m, fmaxf(fmaxf(fabsf(a0), fabsf(a1)), fmaxf(fabsf(a2), fabsf(a3))));
    }
    #pragma unroll
    for (int off = 32; off > 0; off >>= 1) m = fmaxf(m, __shfl_xor(m, off, 64));
    const int lane = tid & 63, wid = tid >> 6;
    if (lane == 0) wmax[wid] = m;
    __syncthreads();
    if (tid == 0)
        xs[row] = fmaxf(fmaxf(wmax[0], wmax[1]), fmaxf(wmax[2], wmax[3]));

    if (tid < N_OUT) xo[row * N_OUT + tid] = xr[oidx[tid]];
}

// ---------------- Kernel 1b: quantize + fragment-order transpose store ----------------
// 256 blocks = 8 rowgrps x 32 kslices(128 k). Coalesced x reads, LDS transpose
// (XOR-swizzled 16B chunks), contiguous 1KB-per-wave XQT writes.
// XQT layout: ks32 tile (8 KB) = [rowgrp][slot = khalf*32 + row&31][16B].
__global__ __launch_bounds__(256) void oal_qtile(
    const float* __restrict__ x, const int* __restrict__ oidx,
    const float* __restrict__ xs, int8_t* __restrict__ xqt)
{
    const int rg  = blockIdx.x >> 5;   // 0..7  (32 rows)
    const int ksl = blockIdx.x & 31;   // 0..31 (128 k)
    const int tid = threadIdx.x;
    __shared__ unsigned char fl[128];
    __shared__ __align__(16) int8_t T[32 * 128];

    if (tid < 128) fl[tid] = 0;
    __syncthreads();
    if (tid < N_OUT) {
        const int ix = oidx[tid];
        if ((ix >> 7) == ksl) fl[ix & 127] = 1;
    }
    __syncthreads();

    const int row_l = tid >> 3, kc = tid & 7;
    const int row = rg * 32 + row_l;
    const float safe = fmaxf(xs[row], 1e-8f);
    const float4* src = reinterpret_cast<const float4*>(
        x + (size_t)row * IN_F + ksl * 128 + kc * 16);
    float4 v[4];
    #pragma unroll
    for (int i = 0; i < 4; ++i) v[i] = src[i];

    const float* vv = reinterpret_cast<const float*>(v);
    unsigned pk[4];
    #pragma unroll
    for (int wds = 0; wds < 4; ++wds) {
        int q[4];
        #pragma unroll
        for (int j = 0; j < 4; ++j) {
            const int i = wds * 4 + j;
            const float val = fl[kc * 16 + i] ? 0.0f : vv[i];
            float t = val / safe * 127.0f;            // exact reference order
            t = fminf(127.0f, fmaxf(-127.0f, rintf(t)));
            q[j] = (int)t;
        }
        pk[wds] = (unsigned)((q[0] & 255) | ((q[1] & 255) << 8)
                 | ((q[2] & 255) << 16) | ((q[3] & 255) << 24));
    }
    *reinterpret_cast<uint4*>(&T[row_l * 128 + ((kc ^ (row_l & 7)) * 16)]) =
        make_uint4(pk[0], pk[1], pk[2], pk[3]);
    __syncthreads();

    // write out: tile = local ks32 (0..3), slot a = khalf*32 + row
    const int tile = tid >> 6, a = tid & 63;
    const int rr = a & 31;
    const int chunk = tile * 2 + (a >> 5);
    uint4 val = *reinterpret_cast<const uint4*>(&T[rr * 128 + ((chunk ^ (rr & 7)) * 16)]);
    *reinterpret_cast<uint4*>(xqt + (size_t)(ksl * 4 + tile) * 8192 + rg * 1024 + a * 16) = val;
}

// ---------------- Kernel 2: int8 MFMA GEMM, split-K ----------------
// grid 256 = 32 n-tiles (BN=128) x 8 k-slices (512 k). 512 threads, 8 waves
// = 4 row-groups (64 rows) x 2 col-groups (64 cols), 32x32x32 i8 MFMA.
template<int MODE>
__global__ __launch_bounds__(512, 1) void oal_gemm(
    const int8_t* __restrict__ xqt, const int* __restrict__ wgt,
    int* __restrict__ pout)
{
    __shared__ __align__(16) int8_t sm[131072];
    int8_t* As = sm;           // 2 bufs x 32 KB
    int8_t* Bs = sm + 65536;   // 16 ks32 x 4 colgrp x 1024 B

    const int bn = blockIdx.x;
    const int ntile = bn & 31, kslice = bn >> 5;
    const int n0 = ntile * 128;
    const int tid = threadIdx.x, lane = tid & 63, wv = tid >> 6;
    const int mg = wv & 3, ng = wv >> 2;
    const int l31 = lane & 31, lh = lane >> 5;

    auto issueA = [&](int h) {   // chunk h = 4 ks32 = 32 KB, linear copy
        const int8_t* s = xqt + ((size_t)(kslice * 16 + h * 4) << 13) + tid * 16;
        int8_t* d = As + ((h & 1) << 15) + tid * 16;
        gll16(s, d);
        gll16(s + 8192, d + 8192);
        gll16(s + 16384, d + 16384);
        gll16(s + 24576, d + 24576);
    };
    issueA(0);

    // ---- B stage ----
    {
        const int cbase = wv * 16;
        #pragma unroll
        for (int g = 0; g < 4; ++g) {
            int4 t[8];
            #pragma unroll
            for (int j = 0; j < 8; ++j) {
                const int q = g * 8 + j;
                const int c = cbase + (q & 15);
                const int ih = q >> 4;
                t[j] = *reinterpret_cast<const int4*>(
                    wgt + (size_t)(n0 + c) * IN_F + kslice * 512 + ih * 256 + lane * 4);
            }
            #pragma unroll
            for (int j = 0; j < 8; ++j) {
                const int q = g * 8 + j;
                const int c = cbase + (q & 15);
                const int ih = q >> 4;
                unsigned pk = (unsigned)((t[j].x & 255) | ((t[j].y & 255) << 8)
                             | ((t[j].z & 255) << 16) | ((t[j].w & 255) << 24));
                const int ks32l = ih * 8 + (lane >> 3);
                const int addr = ks32l * 4096 + (c >> 5) * 1024
                               + (((lane >> 2) & 1) * 32 + ((c & 31) ^ (lane >> 3))) * 16
                               + (lane & 3) * 4;
                *reinterpret_cast<unsigned*>(Bs + addr) = pk;
            }
        }
    }
    __syncthreads();    // chunk0 A arrived, B packed

    // ---- compute: 16 ks32 steps ----
    v16i acc00 = {}, acc01 = {}, acc10 = {}, acc11 = {};
    const int aoff = (2 * mg) * 1024 + lane * 16;
    #pragma unroll
    for (int h = 0; h < 4; ++h) {
        if (h < 3) issueA(h + 1);
        const int8_t* At = As + ((h & 1) << 15);
        #pragma unroll
        for (int loc = 0; loc < 4; ++loc) {
            const int ks32g = h * 4 + loc;
            const int s7 = ks32g & 7;
            const int8_t* Ap = At + loc * 8192 + aoff;
            const int8_t* Bp = Bs + ks32g * 4096 + (lh * 32 + (l31 ^ s7)) * 16;
            v4i a0 = *reinterpret_cast<const v4i*>(Ap);
            v4i a1 = *reinterpret_cast<const v4i*>(Ap + 1024);
            v4i b0 = *reinterpret_cast<const v4i*>(Bp + (2 * ng) * 1024);
            v4i b1 = *reinterpret_cast<const v4i*>(Bp + (2 * ng + 1) * 1024);
            acc00 = __builtin_amdgcn_mfma_i32_32x32x32_i8(a0, b0, acc00, 0, 0, 0);
            acc01 = __builtin_amdgcn_mfma_i32_32x32x32_i8(a0, b1, acc01, 0, 0, 0);
            acc10 = __builtin_amdgcn_mfma_i32_32x32x32_i8(a1, b0, acc10, 0, 0, 0);
            acc11 = __builtin_amdgcn_mfma_i32_32x32x32_i8(a1, b1, acc11, 0, 0, 0);
        }
        if (h < 3) __syncthreads();
    }

    // ---- write int32 partials ----
    const int colb = n0 + ng * 64 + l31;
    const int rowb = mg * 64 + 4 * lh;
#define OUTW(ACC, MF, NF) { _Pragma("unroll") \
    for (int r = 0; r < 16; ++r) { \
        const int rr = rowb + (MF)*32 + (r & 3) + ((r >> 2) << 3); \
        const size_t off = (size_t)rr * OUT_F + colb + (NF)*32; \
        if (MODE == 0) pout[(size_t)kslice * ((size_t)TOK * OUT_F) + off] = ACC[r]; \
        else atomicAdd(pout + off, ACC[r]); \
    } }
    OUTW(acc00,0,0) OUTW(acc01,0,1) OUTW(acc10,1,0) OUTW(acc11,1,1)
#undef OUTW
}

// ---------------- Kernel 3: reduce partials + fused epilogue ----------------
template<int MODE>
__global__ __launch_bounds__(256) void oal_epi(
    float* __restrict__ outp, const int* __restrict__ part,
    const float* __restrict__ xs, const float* __restrict__ wscale,
    const float* __restrict__ ow, const float* __restrict__ bias,
    const float* __restrict__ xo)
{
    const int rb = blockIdx.x >> 3;      // rows rb*8 .. +8
    const int cb = blockIdx.x & 7;       // cols cb*512 .. +512
    const int tid = threadIdx.x;
    const int c0 = cb * 512 + tid * 2;

    __shared__ float sxo[8][32];
    __shared__ float sxs[8];
    if (tid < 64) {
        const int rr = tid >> 3, jj = tid & 7;
        *reinterpret_cast<float4*>(&sxo[rr][jj * 4]) =
            *reinterpret_cast<const float4*>(xo + (size_t)(rb * 8 + rr) * N_OUT + jj * 4);
    }
    if (tid < 8) sxs[tid] = xs[rb * 8 + tid];
    __syncthreads();

    float o0[32], o1[32];
    #pragma unroll
    for (int j = 0; j < 8; ++j) {
        float4 f0 = reinterpret_cast<const float4*>(ow + (size_t)c0 * N_OUT)[j];
        float4 f1 = reinterpret_cast<const float4*>(ow + (size_t)(c0 + 1) * N_OUT)[j];
        o0[j*4+0]=f0.x; o0[j*4+1]=f0.y; o0[j*4+2]=f0.z; o0[j*4+3]=f0.w;
        o1[j*4+0]=f1.x; o1[j*4+1]=f1.y; o1[j*4+2]=f1.z; o1[j*4+3]=f1.w;
    }
    const float wsc0 = wscale[c0]     * (1.0f / 16129.0f);
    const float wsc1 = wscale[c0 + 1] * (1.0f / 16129.0f);
    const float bo0 = bias[c0], bo1 = bias[c0 + 1];

    #pragma unroll
    for (int r = 0; r < 8; ++r) {
        const int row = rb * 8 + r;
        const size_t off = (size_t)row * OUT_F + c0;
        int px = 0, py = 0;
        if (MODE == 0) {
            #pragma unroll
            for (int s2 = 0; s2 < 8; ++s2) {
                int2 t = *reinterpret_cast<const int2*>(
                    part + (size_t)s2 * ((size_t)TOK * OUT_F) + off);
                px += t.x; py += t.y;
            }
        } else {
            int2 t = *reinterpret_cast<const int2*>(reinterpret_cast<const int*>(outp) + off);
            px = t.x; py = t.y;
        }
        float d0 = 0.f, d1 = 0.f;
        #pragma unroll
        for (int k = 0; k < 32; ++k) {
            const float xv = sxo[r][k];
            d0 += xv * o0[k]; d1 += xv * o1[k];
        }
        const float s = sxs[r];
        float2 res;
        res.x = (float)px * (s * wsc0) + d0 + bo0;
        res.y = (float)py * (s * wsc1) + d1 + bo1;
        *reinterpret_cast<float2*>(outp + off) = res;
    }
}

extern "C" void kernel_launch(void* const* d_in, const int* in_sizes, int n_in,
                              void* d_out, int out_size, void* d_ws, size_t ws_size,
                              hipStream_t stream) {
    const float* x      = (const float*)d_in[0];
    const int*   w      = (const int*)  d_in[1];
    const float* wscale = (const float*)d_in[2];
    const int*   oidx   = (const int*)  d_in[3];
    const float* ow     = (const float*)d_in[4];
    const float* bias   = (const float*)d_in[5];
    float* out = (float*)d_out;

    int8_t* xqt = (int8_t*)d_ws;
    float*  xs  = (float*)((char*)d_ws + (1 << 20));
    float*  xo  = (float*)((char*)d_ws + (1 << 20) + 1024);
    int*    P2  = (int*)  ((char*)d_ws + (1 << 20) + 1024 + 32768);
    const size_t need = (size_t)(1 << 20) + 1024 + 32768 + (size_t)8 * TOK * OUT_F * 4;

    oal_absmax<<<TOK, 256, 0, stream>>>(x, oidx, xs, xo);
    oal_qtile<<<256, 256, 0, stream>>>(x, oidx, xs, xqt);
    if (ws_size >= need) {
        oal_gemm<0><<<256, 512, 0, stream>>>(xqt, w, P2);
        oal_epi<0><<<256, 256, 0, stream>>>(out, P2, xs, wscale, ow, bias, xo);
    } else {
        hipMemsetAsync(d_out, 0, (size_t)TOK * OUT_F * 4, stream);
        oal_gemm<1><<<256, 512, 0, stream>>>(xqt, w, (int*)d_out);
        oal_epi<1><<<256, 256, 0, stream>>>(out, (const int*)d_out, xs, wscale, ow, bias, xo);
    }
}